// Round 9
// baseline (409.427 us; speedup 1.0000x reference)
//
#include <hip/hip_runtime.h>

// GCN 2-layer on MI355X — Round 9: output-split pass C (coalesced CSR build),
// zero per-edge atomics in aggregation, XCD-swizzled L2 reuse.
//
// g[j] = x[j]*dinv[j].  layer1: hs2 via relu(dinv*(sum g)+b1)@W2*dinv
// layer2: out[i] = dinv[i]*(sum hs2[src]+hs2[i]) + b2
//
// Pass A: bucket by dp = dst>>11 (P=98), packed = (ld<<18)|src.
// Pass C (sortC): block=(dp,q), q = 256-ld output range. Phase1: stream dp
//   list, hist own lds + count edges below range (-> base, rowptr, dinv, g).
//   Phase2: re-stream, place into LDS stage, flush coalesced to srcsorted.
//   Swizzle b = q*104+dp keeps all q-blocks of a dp on one XCD (104%8==0).
// Agg: thread = node, register accumulation, fused dense epilogues.

#define EPB   8192   // edges per pass-A block
#define PART  2048   // nodes per partition
#define LPBIT 11
#define SRCB  18     // src bits in packed
#define DPSTRIDE 104 // swizzle stride (multiple of 8 >= P)
#define STCAP 12288  // staging words (48 KB); avg fill 8192

// ---------------- Pass A ----------------

__global__ __launch_bounds__(512) void countA_kernel(
    const int* __restrict__ dst, int* __restrict__ cntmat, int E, int P) {
    __shared__ int cnt[128];
    int tid = threadIdx.x;
    if (tid < 128) cnt[tid] = 0;
    __syncthreads();
    int base = blockIdx.x * EPB;
    #pragma unroll
    for (int k = 0; k < EPB; k += 512) {
        int e = base + k + tid;
        if (e < E) atomicAdd(&cnt[dst[e] >> LPBIT], 1);
    }
    __syncthreads();
    int* row = cntmat + (size_t)blockIdx.x * P;
    if (tid < P) row[tid] = cnt[tid];
}

__global__ __launch_bounds__(256) void colscanA_kernel(
    int* __restrict__ cntmat, int* __restrict__ colTotal, int B, int P) {
    __shared__ int sdata[256];
    int p = blockIdx.x, tid = threadIdx.x;
    int v[4];
    int s = 0;
    #pragma unroll
    for (int k = 0; k < 4; k++) {
        int b = tid * 4 + k;
        v[k] = (b < B) ? cntmat[(size_t)b * P + p] : 0;
        s += v[k];
    }
    int x = s;
    sdata[tid] = x;
    __syncthreads();
    for (int off = 1; off < 256; off <<= 1) {
        int t = (tid >= off) ? sdata[tid - off] : 0;
        __syncthreads();
        x += t;
        sdata[tid] = x;
        __syncthreads();
    }
    int run = x - s;
    #pragma unroll
    for (int k = 0; k < 4; k++) {
        int b = tid * 4 + k;
        if (b < B) cntmat[(size_t)b * P + p] = run;
        run += v[k];
    }
    if (tid == 255) colTotal[p] = x;
}

__global__ __launch_bounds__(256) void totalscanA_kernel(
    const int* __restrict__ colTotal, int* __restrict__ colStart,
    int P, int E) {
    __shared__ int sdata[256];
    int tid = threadIdx.x;
    int v[4];
    int s = 0;
    #pragma unroll
    for (int k = 0; k < 4; k++) {
        int i = tid * 4 + k;
        v[k] = (i < P) ? colTotal[i] : 0;
        s += v[k];
    }
    int x = s;
    sdata[tid] = x;
    __syncthreads();
    for (int off = 1; off < 256; off <<= 1) {
        int t = (tid >= off) ? sdata[tid - off] : 0;
        __syncthreads();
        x += t;
        sdata[tid] = x;
        __syncthreads();
    }
    int run = x - s;
    #pragma unroll
    for (int k = 0; k < 4; k++) {
        int i = tid * 4 + k;
        if (i < P) colStart[i] = run;
        run += v[k];
    }
    if (tid == 0) colStart[P] = E;
}

__global__ __launch_bounds__(512) void scatterA_kernel(
    const int* __restrict__ src, const int* __restrict__ dst,
    const int* __restrict__ cntmat, const int* __restrict__ colStart,
    unsigned* __restrict__ packed, int E, int P) {
    __shared__ int cur[128];
    int tid = threadIdx.x;
    if (tid < P) cur[tid] = colStart[tid] + cntmat[(size_t)blockIdx.x * P + tid];
    __syncthreads();
    int base = blockIdx.x * EPB;
    #pragma unroll
    for (int k = 0; k < EPB; k += 512) {
        int e = base + k + tid;
        if (e < E) {
            int d = dst[e];
            int pos = atomicAdd(&cur[d >> LPBIT], 1);
            packed[pos] = ((unsigned)(d & (PART - 1)) << SRCB) | (unsigned)src[e];
        }
    }
}

// ---------------- Pass C: output-split CSR build ----------------
// block b -> (q = b/DPSTRIDE, dp = b%DPSTRIDE); handles localdst range
// [q*256, q*256+256). Emits srcsorted (coalesced), rowptr, dinv, g.
__global__ __launch_bounds__(512) void sortC_kernel(
    const unsigned* __restrict__ packed, const int* __restrict__ colStart,
    const float* __restrict__ x, int* __restrict__ rowptr,
    int* __restrict__ srcsorted, float* __restrict__ dinv,
    float* __restrict__ g, int n, int P) {
    __shared__ int hist[256];
    __shared__ int sdata[256];
    __shared__ int cur[256];
    __shared__ int below_s;
    __shared__ unsigned stage[STCAP];
    int b = blockIdx.x;
    int q = b / DPSTRIDE, dp = b % DPSTRIDE;
    if (dp >= P) return;
    int tid = threadIdx.x;
    if (tid < 256) hist[tid] = 0;
    if (tid == 0) below_s = 0;
    __syncthreads();
    int s0 = colStart[dp], s1 = colStart[dp + 1];
    // Phase 1: histogram own-range lds; count edges below my range.
    int myBelow = 0;
    for (int i = s0 + tid; i < s1; i += 512) {
        unsigned w = packed[i];
        int ldq = (int)(w >> (SRCB + 8));
        if (ldq == q) atomicAdd(&hist[(w >> SRCB) & 255], 1);
        else if (ldq < q) myBelow++;
    }
    #pragma unroll
    for (int off = 32; off > 0; off >>= 1) myBelow += __shfl_down(myBelow, off);
    if ((tid & 63) == 0) atomicAdd(&below_s, myBelow);
    __syncthreads();
    int base = s0 + below_s;
    // Scan hist[256] (inclusive) with threads 0..255.
    int deg = 0, x_ = 0;
    if (tid < 256) { deg = hist[tid]; x_ = deg; sdata[tid] = x_; }
    __syncthreads();
    for (int off = 1; off < 256; off <<= 1) {
        int t = (tid < 256 && tid >= off) ? sdata[tid - off] : 0;
        __syncthreads();
        if (tid < 256) { x_ += t; sdata[tid] = x_; }
        __syncthreads();
    }
    int total = sdata[255];
    if (tid < 256) {
        int ex = x_ - deg;
        cur[tid] = ex;
        int node = (dp << LPBIT) + (q << 8) + tid;
        if (node <= n) rowptr[node] = base + ex;
        if (node < n) {
            float d = rsqrtf((float)deg + 1.0f);  // +1 self-loop
            dinv[node] = d;
            float2 xv = ((const float2*)x)[node];
            ((float2*)g)[node] = make_float2(xv.x * d, xv.y * d);
        }
    }
    __syncthreads();
    // Phase 2: place own-range edges into LDS stage (or direct on overflow).
    bool ovf = total > STCAP;
    for (int i = s0 + tid; i < s1; i += 512) {
        unsigned w = packed[i];
        if ((int)(w >> (SRCB + 8)) == q) {
            int pos = atomicAdd(&cur[(w >> SRCB) & 255], 1);
            unsigned srcv = w & ((1u << SRCB) - 1);
            if (!ovf) stage[pos] = srcv;
            else srcsorted[base + pos] = srcv;
        }
    }
    __syncthreads();
    if (!ovf)
        for (int j = tid; j < total; j += 512) srcsorted[base + j] = (int)stage[j];
}

// ---------------- Aggregation (atomic-free) ----------------

__global__ __launch_bounds__(512) void agg1_kernel(
    const int* __restrict__ rowptr, const int* __restrict__ srcsorted,
    const float* __restrict__ g, const float* __restrict__ dinv,
    const float* __restrict__ W1, const float* __restrict__ b1,
    const float* __restrict__ W2, float* __restrict__ hs2, int n) {
    int i = blockIdx.x * 512 + threadIdx.x;
    if (i >= n) return;
    int p0 = rowptr[i], p1 = rowptr[i + 1];
    const float2* gp = (const float2*)g;
    float s0 = 0.0f, s1 = 0.0f;
    int p = p0;
    for (; p + 4 <= p1; p += 4) {
        int a = srcsorted[p], b = srcsorted[p + 1];
        int c = srcsorted[p + 2], e = srcsorted[p + 3];
        float2 v0 = gp[a], v1 = gp[b], v2 = gp[c], v3 = gp[e];
        s0 += v0.x + v1.x + v2.x + v3.x;
        s1 += v0.y + v1.y + v2.y + v3.y;
    }
    for (; p < p1; p++) {
        float2 v = gp[srcsorted[p]];
        s0 += v.x;
        s1 += v.y;
    }
    float d = dinv[i];
    float2 gi = gp[i];
    s0 = (s0 + gi.x) * d;
    s1 = (s1 + gi.y) * d;
    float h[8];
    #pragma unroll
    for (int f = 0; f < 8; f++)
        h[f] = fmaxf(s0 * W1[f] + s1 * W1[8 + f] + b1[f], 0.0f);
    float oc[4];
    #pragma unroll
    for (int k = 0; k < 4; k++) {
        float a = 0.0f;
        #pragma unroll
        for (int f = 0; f < 8; f++) a += h[f] * W2[4 * f + k];
        oc[k] = a * d;
    }
    float4 o;
    o.x = oc[0]; o.y = oc[1]; o.z = oc[2]; o.w = oc[3];
    *(float4*)(hs2 + 4 * (size_t)i) = o;
}

__global__ __launch_bounds__(512) void agg2_kernel(
    const int* __restrict__ rowptr, const int* __restrict__ srcsorted,
    const float* __restrict__ hs2, const float* __restrict__ dinv,
    const float* __restrict__ b2, float* __restrict__ out, int n) {
    int i = blockIdx.x * 512 + threadIdx.x;
    if (i >= n) return;
    int p0 = rowptr[i], p1 = rowptr[i + 1];
    const float4* hp = (const float4*)hs2;
    float s0 = 0.0f, s1 = 0.0f, s2 = 0.0f, s3 = 0.0f;
    int p = p0;
    for (; p + 4 <= p1; p += 4) {
        int a = srcsorted[p], b = srcsorted[p + 1];
        int c = srcsorted[p + 2], e = srcsorted[p + 3];
        float4 v0 = hp[a], v1 = hp[b], v2 = hp[c], v3 = hp[e];
        s0 += v0.x + v1.x + v2.x + v3.x;
        s1 += v0.y + v1.y + v2.y + v3.y;
        s2 += v0.z + v1.z + v2.z + v3.z;
        s3 += v0.w + v1.w + v2.w + v3.w;
    }
    for (; p < p1; p++) {
        float4 v = hp[srcsorted[p]];
        s0 += v.x; s1 += v.y; s2 += v.z; s3 += v.w;
    }
    float d = dinv[i];
    float4 hi = hp[i];
    float4 o;
    o.x = d * (s0 + hi.x) + b2[0];
    o.y = d * (s1 + hi.y) + b2[1];
    o.z = d * (s2 + hi.z) + b2[2];
    o.w = d * (s3 + hi.w) + b2[3];
    *(float4*)(out + 4 * (size_t)i) = o;
}

extern "C" void kernel_launch(void* const* d_in, const int* in_sizes, int n_in,
                              void* d_out, int out_size, void* d_ws, size_t ws_size,
                              hipStream_t stream) {
    const float* x   = (const float*)d_in[0];
    const int*   ei  = (const int*)d_in[1];
    const float* W1  = (const float*)d_in[2];
    const float* b1  = (const float*)d_in[3];
    const float* W2  = (const float*)d_in[4];
    const float* b2  = (const float*)d_in[5];
    float* out = (float*)d_out;

    const int n = in_sizes[0] / 2;  // x is [N,2]
    const int E = in_sizes[1] / 2;  // edge_index is [2,E]
    const int* src = ei;
    const int* dst = ei + E;

    const int P  = (n + PART - 1) >> LPBIT;  // 98
    const int B1 = (E + EPB - 1) / EPB;      // 782

    int* ws = (int*)d_ws;
    int* colTotal = ws;                                      // 1024
    int* colStart = ws + 1024;                               // 1024
    int* cntmatA  = ws + 2048;                               // B1*P
    size_t cmsz = (((size_t)B1 * P) + 3) & ~(size_t)3;
    int* rowptr = cntmatA + cmsz;                            // n+4
    unsigned* packed = (unsigned*)(rowptr + n + 4);          // E
    int* srcsorted = (int*)(packed + E);                     // E
    size_t nd = (size_t)P << LPBIT;                          // 200704
    float* dinv = (float*)(srcsorted + E);                   // nd
    float* g    = dinv + nd;                                 // 2*nd
    float* hs2  = g + 2 * nd;                                // 4*nd

    const int gN = (n + 511) / 512;

    countA_kernel    <<<B1, 512, 0, stream>>>(dst, cntmatA, E, P);
    colscanA_kernel  <<<P, 256, 0, stream>>>(cntmatA, colTotal, B1, P);
    totalscanA_kernel<<<1, 256, 0, stream>>>(colTotal, colStart, P, E);
    scatterA_kernel  <<<B1, 512, 0, stream>>>(src, dst, cntmatA, colStart, packed, E, P);
    sortC_kernel     <<<8 * DPSTRIDE, 512, 0, stream>>>(packed, colStart, x,
                                                        rowptr, srcsorted, dinv, g, n, P);
    agg1_kernel      <<<gN, 512, 0, stream>>>(rowptr, srcsorted, g, dinv, W1, b1, W2, hs2, n);
    agg2_kernel      <<<gN, 512, 0, stream>>>(rowptr, srcsorted, hs2, dinv, b2, out, n);
}

// Round 10
// 246.624 us; speedup vs baseline: 1.6601x; 1.6601x over previous
//
#include <hip/hip_runtime.h>

// GCN 2-layer on MI355X — Round 10: pass A (vectorized bucket sort by dst
// partition) + purely LOCAL pass C (in-place LDS counting sort, write-amp 1,
// no global cursors) -> 4-run CSR; atomic-free register aggregation.
//
// g[j] = x[j]*dinv[j].  layer1: hs2 via relu(dinv*(sum g)+b1)@W2*dinv
// layer2: out[i] = dinv[i]*(sum hs2[src]+hs2[i]) + b2
//
// Pass A: bucket by dp = dst>>11 (P=98), packed = (ld<<18)|src, int4 loads.
// localC: block=(dp,b), b<4: sort its own 16k-edge range by ld entirely in
//   LDS (hist 2048 -> scan -> stage -> coalesced flush to same range);
//   emits runStart[(dp*4+b)*2049 + ld] (+end sentinel).
// Agg: thread = node, 4 runs of ~8 edges, register acc, fused epilogues.
//
// ws: colTotal|colStart|cntmatA[B1*P]|runStart[P*4*2049]|packed[E]|srcsorted[E]
//     (dinv|g|hs2 overlay packed after localC)   ~55 MB

#define EPB   8192   // edges per pass-A block
#define PART  2048   // nodes per partition
#define LPBIT 11
#define SRCB  18     // src bits in packed
#define BC    4      // localC sub-blocks per dp
#define RSTR  2049   // runStart stride per (dp,b)
#define STCAP 17408  // LDS stage words (68 KB); max expected ~16.6k

// ---------------- Pass A ----------------

__global__ __launch_bounds__(512) void countA_kernel(
    const int* __restrict__ dst, int* __restrict__ cntmat, int E, int P) {
    __shared__ int cnt[128];
    int tid = threadIdx.x;
    if (tid < 128) cnt[tid] = 0;
    __syncthreads();
    int nv4 = E >> 2;
    int b4 = (blockIdx.x * EPB) >> 2;
    int e4 = min(b4 + (EPB >> 2), nv4);
    const int4* d4 = (const int4*)dst;
    #pragma unroll
    for (int k = 0; k < (EPB >> 2); k += 512) {
        int i = b4 + k + tid;
        if (i < e4) {
            int4 d = d4[i];
            atomicAdd(&cnt[d.x >> LPBIT], 1);
            atomicAdd(&cnt[d.y >> LPBIT], 1);
            atomicAdd(&cnt[d.z >> LPBIT], 1);
            atomicAdd(&cnt[d.w >> LPBIT], 1);
        }
    }
    if (blockIdx.x == gridDim.x - 1) {  // scalar tail (E % 4)
        int e = (nv4 << 2) + tid;
        if (e < E) atomicAdd(&cnt[dst[e] >> LPBIT], 1);
    }
    __syncthreads();
    int* row = cntmat + (size_t)blockIdx.x * P;
    if (tid < P) row[tid] = cnt[tid];
}

__global__ __launch_bounds__(256) void colscanA_kernel(
    int* __restrict__ cntmat, int* __restrict__ colTotal, int B, int P) {
    __shared__ int sdata[256];
    int p = blockIdx.x, tid = threadIdx.x;
    int v[4];
    int s = 0;
    #pragma unroll
    for (int k = 0; k < 4; k++) {
        int b = tid * 4 + k;
        v[k] = (b < B) ? cntmat[(size_t)b * P + p] : 0;
        s += v[k];
    }
    int x = s;
    sdata[tid] = x;
    __syncthreads();
    for (int off = 1; off < 256; off <<= 1) {
        int t = (tid >= off) ? sdata[tid - off] : 0;
        __syncthreads();
        x += t;
        sdata[tid] = x;
        __syncthreads();
    }
    int run = x - s;
    #pragma unroll
    for (int k = 0; k < 4; k++) {
        int b = tid * 4 + k;
        if (b < B) cntmat[(size_t)b * P + p] = run;
        run += v[k];
    }
    if (tid == 255) colTotal[p] = x;
}

__global__ __launch_bounds__(256) void totalscanA_kernel(
    const int* __restrict__ colTotal, int* __restrict__ colStart,
    int P, int E) {
    __shared__ int sdata[256];
    int tid = threadIdx.x;
    int v[4];
    int s = 0;
    #pragma unroll
    for (int k = 0; k < 4; k++) {
        int i = tid * 4 + k;
        v[k] = (i < P) ? colTotal[i] : 0;
        s += v[k];
    }
    int x = s;
    sdata[tid] = x;
    __syncthreads();
    for (int off = 1; off < 256; off <<= 1) {
        int t = (tid >= off) ? sdata[tid - off] : 0;
        __syncthreads();
        x += t;
        sdata[tid] = x;
        __syncthreads();
    }
    int run = x - s;
    #pragma unroll
    for (int k = 0; k < 4; k++) {
        int i = tid * 4 + k;
        if (i < P) colStart[i] = run;
        run += v[k];
    }
    if (tid == 0) colStart[P] = E;
}

__global__ __launch_bounds__(512) void scatterA_kernel(
    const int* __restrict__ src, const int* __restrict__ dst,
    const int* __restrict__ cntmat, const int* __restrict__ colStart,
    unsigned* __restrict__ packed, int E, int P) {
    __shared__ int cur[128];
    int tid = threadIdx.x;
    if (tid < P) cur[tid] = colStart[tid] + cntmat[(size_t)blockIdx.x * P + tid];
    __syncthreads();
    int nv4 = E >> 2;
    int b4 = (blockIdx.x * EPB) >> 2;
    int e4 = min(b4 + (EPB >> 2), nv4);
    const int4* d4 = (const int4*)dst;
    const int4* s4 = (const int4*)src;
    #pragma unroll
    for (int k = 0; k < (EPB >> 2); k += 512) {
        int i = b4 + k + tid;
        if (i < e4) {
            int4 d = d4[i];
            int4 sv = s4[i];
            int p0 = atomicAdd(&cur[d.x >> LPBIT], 1);
            packed[p0] = ((unsigned)(d.x & (PART - 1)) << SRCB) | (unsigned)sv.x;
            int p1 = atomicAdd(&cur[d.y >> LPBIT], 1);
            packed[p1] = ((unsigned)(d.y & (PART - 1)) << SRCB) | (unsigned)sv.y;
            int p2 = atomicAdd(&cur[d.z >> LPBIT], 1);
            packed[p2] = ((unsigned)(d.z & (PART - 1)) << SRCB) | (unsigned)sv.z;
            int p3 = atomicAdd(&cur[d.w >> LPBIT], 1);
            packed[p3] = ((unsigned)(d.w & (PART - 1)) << SRCB) | (unsigned)sv.w;
        }
    }
    if (blockIdx.x == gridDim.x - 1) {  // scalar tail
        int e = (nv4 << 2) + tid;
        if (e < E) {
            int d = dst[e];
            int pos = atomicAdd(&cur[d >> LPBIT], 1);
            packed[pos] = ((unsigned)(d & (PART - 1)) << SRCB) | (unsigned)src[e];
        }
    }
}

// ---------------- localC: in-place LDS counting sort per 16k range --------

__global__ __launch_bounds__(512) void localC_kernel(
    const unsigned* __restrict__ packed, const int* __restrict__ colStart,
    int* __restrict__ runStart, int* __restrict__ srcsorted) {
    __shared__ int hist[PART];      // counts -> absolute cursors
    __shared__ int sdata[512];
    __shared__ unsigned stage[STCAP];
    int tid = threadIdx.x;
    int dp = blockIdx.x >> 2, b = blockIdx.x & (BC - 1);
    int s0 = colStart[dp], len = colStart[dp + 1] - s0;
    int lo = s0 + (int)(((long long)len * b) / BC);
    int hi = s0 + (int)(((long long)len * (b + 1)) / BC);
    for (int k = tid; k < PART; k += 512) hist[k] = 0;
    __syncthreads();
    for (int i = lo + tid; i < hi; i += 512)
        atomicAdd(&hist[packed[i] >> SRCB], 1);
    __syncthreads();
    // exclusive scan of hist[2048], 4 elems/thread
    int off = tid * 4;
    int v0 = hist[off], v1 = hist[off + 1], v2 = hist[off + 2], v3 = hist[off + 3];
    int s = v0 + v1 + v2 + v3;
    int x = s;
    sdata[tid] = x;
    __syncthreads();
    for (int o = 1; o < 512; o <<= 1) {
        int t = (tid >= o) ? sdata[tid - o] : 0;
        __syncthreads();
        x += t;
        sdata[tid] = x;
        __syncthreads();
    }
    int run = x - s;  // exclusive prefix of this thread's 4 buckets
    int* rs = runStart + (size_t)(dp * BC + b) * RSTR;
    int c0 = lo + run, c1 = c0 + v0, c2 = c1 + v1, c3 = c2 + v2;
    rs[off] = c0; rs[off + 1] = c1; rs[off + 2] = c2; rs[off + 3] = c3;
    __syncthreads();  // all v-reads done before cursor overwrite
    hist[off] = c0; hist[off + 1] = c1; hist[off + 2] = c2; hist[off + 3] = c3;
    if (tid == 0) rs[PART] = hi;  // end sentinel
    __syncthreads();
    // place into LDS stage (absolute pos - lo), then coalesced flush
    int total = hi - lo;
    bool ovf = total > STCAP;
    for (int i = lo + tid; i < hi; i += 512) {
        unsigned w = packed[i];
        int pos = atomicAdd(&hist[w >> SRCB], 1);
        unsigned sv = w & ((1u << SRCB) - 1);
        if (!ovf) stage[pos - lo] = sv;
        else srcsorted[pos] = sv;
    }
    __syncthreads();
    if (!ovf)
        for (int j = tid; j < total; j += 512) srcsorted[lo + j] = (int)stage[j];
}

// ---------------- Node-side (atomic-free) ----------------

__global__ __launch_bounds__(512) void dinvg_kernel(
    const int* __restrict__ runStart, const float* __restrict__ x,
    float* __restrict__ dinv, float* __restrict__ g, int n) {
    int i = blockIdx.x * 512 + threadIdx.x;
    if (i >= n) return;
    int dp = i >> LPBIT, ld = i & (PART - 1);
    int deg = 0;
    #pragma unroll
    for (int b = 0; b < BC; b++) {
        const int* rs = runStart + (size_t)(dp * BC + b) * RSTR + ld;
        deg += rs[1] - rs[0];
    }
    float d = rsqrtf((float)deg + 1.0f);  // +1 self-loop
    dinv[i] = d;
    float2 xv = ((const float2*)x)[i];
    ((float2*)g)[i] = make_float2(xv.x * d, xv.y * d);
}

// thread = node: 4 runs, gather g[src], register acc + fused W1/ReLU/W2.
__global__ __launch_bounds__(512) void agg1_kernel(
    const int* __restrict__ runStart, const int* __restrict__ srcsorted,
    const float* __restrict__ g, const float* __restrict__ dinv,
    const float* __restrict__ W1, const float* __restrict__ b1,
    const float* __restrict__ W2, float* __restrict__ hs2, int n) {
    int i = blockIdx.x * 512 + threadIdx.x;
    if (i >= n) return;
    int dp = i >> LPBIT, ld = i & (PART - 1);
    const float2* gp = (const float2*)g;
    float s0 = 0.0f, s1 = 0.0f;
    #pragma unroll
    for (int b = 0; b < BC; b++) {
        const int* rs = runStart + (size_t)(dp * BC + b) * RSTR + ld;
        int p0 = rs[0], p1 = rs[1];
        int p = p0;
        for (; p + 4 <= p1; p += 4) {
            int a = srcsorted[p], bb = srcsorted[p + 1];
            int c = srcsorted[p + 2], e = srcsorted[p + 3];
            float2 w0 = gp[a], w1 = gp[bb], w2 = gp[c], w3 = gp[e];
            s0 += w0.x + w1.x + w2.x + w3.x;
            s1 += w0.y + w1.y + w2.y + w3.y;
        }
        for (; p < p1; p++) {
            float2 w = gp[srcsorted[p]];
            s0 += w.x;
            s1 += w.y;
        }
    }
    float d = dinv[i];
    float2 gi = gp[i];
    s0 = (s0 + gi.x) * d;
    s1 = (s1 + gi.y) * d;
    float h[8];
    #pragma unroll
    for (int f = 0; f < 8; f++)
        h[f] = fmaxf(s0 * W1[f] + s1 * W1[8 + f] + b1[f], 0.0f);
    float oc[4];
    #pragma unroll
    for (int k = 0; k < 4; k++) {
        float a = 0.0f;
        #pragma unroll
        for (int f = 0; f < 8; f++) a += h[f] * W2[4 * f + k];
        oc[k] = a * d;
    }
    float4 o;
    o.x = oc[0]; o.y = oc[1]; o.z = oc[2]; o.w = oc[3];
    *(float4*)(hs2 + 4 * (size_t)i) = o;
}

// thread = node: 4 runs, gather hs2[src], write final output.
__global__ __launch_bounds__(512) void agg2_kernel(
    const int* __restrict__ runStart, const int* __restrict__ srcsorted,
    const float* __restrict__ hs2, const float* __restrict__ dinv,
    const float* __restrict__ b2, float* __restrict__ out, int n) {
    int i = blockIdx.x * 512 + threadIdx.x;
    if (i >= n) return;
    int dp = i >> LPBIT, ld = i & (PART - 1);
    const float4* hp = (const float4*)hs2;
    float s0 = 0.0f, s1 = 0.0f, s2 = 0.0f, s3 = 0.0f;
    #pragma unroll
    for (int b = 0; b < BC; b++) {
        const int* rs = runStart + (size_t)(dp * BC + b) * RSTR + ld;
        int p0 = rs[0], p1 = rs[1];
        int p = p0;
        for (; p + 4 <= p1; p += 4) {
            int a = srcsorted[p], bb = srcsorted[p + 1];
            int c = srcsorted[p + 2], e = srcsorted[p + 3];
            float4 w0 = hp[a], w1 = hp[bb], w2 = hp[c], w3 = hp[e];
            s0 += w0.x + w1.x + w2.x + w3.x;
            s1 += w0.y + w1.y + w2.y + w3.y;
            s2 += w0.z + w1.z + w2.z + w3.z;
            s3 += w0.w + w1.w + w2.w + w3.w;
        }
        for (; p < p1; p++) {
            float4 w = hp[srcsorted[p]];
            s0 += w.x; s1 += w.y; s2 += w.z; s3 += w.w;
        }
    }
    float d = dinv[i];
    float4 hi2 = hp[i];
    float4 o;
    o.x = d * (s0 + hi2.x) + b2[0];
    o.y = d * (s1 + hi2.y) + b2[1];
    o.z = d * (s2 + hi2.z) + b2[2];
    o.w = d * (s3 + hi2.w) + b2[3];
    *(float4*)(out + 4 * (size_t)i) = o;
}

extern "C" void kernel_launch(void* const* d_in, const int* in_sizes, int n_in,
                              void* d_out, int out_size, void* d_ws, size_t ws_size,
                              hipStream_t stream) {
    const float* x   = (const float*)d_in[0];
    const int*   ei  = (const int*)d_in[1];
    const float* W1  = (const float*)d_in[2];
    const float* b1  = (const float*)d_in[3];
    const float* W2  = (const float*)d_in[4];
    const float* b2  = (const float*)d_in[5];
    float* out = (float*)d_out;

    const int n = in_sizes[0] / 2;  // x is [N,2]
    const int E = in_sizes[1] / 2;  // edge_index is [2,E]
    const int* src = ei;
    const int* dst = ei + E;

    const int P  = (n + PART - 1) >> LPBIT;  // 98
    const int B1 = (E + EPB - 1) / EPB;      // 782

    int* ws = (int*)d_ws;
    int* colTotal = ws;                                      // 1024
    int* colStart = ws + 1024;                               // 1024
    int* cntmatA  = ws + 2048;                               // B1*P
    size_t cmsz = (((size_t)B1 * P) + 3) & ~(size_t)3;
    int* runStart = cntmatA + cmsz;                          // P*BC*RSTR
    size_t rssz = (((size_t)P * BC * RSTR) + 3) & ~(size_t)3;
    unsigned* packed = (unsigned*)(runStart + rssz);         // E
    int* srcsorted = (int*)(packed + E);                     // E
    // packed region is dead after localC; overlay node buffers (7*nd <= E):
    size_t nd = (size_t)P << LPBIT;                          // 200704
    float* dinv = (float*)packed;                            // nd
    float* g    = dinv + nd;                                 // 2*nd
    float* hs2  = g + 2 * nd;                                // 4*nd

    const int gN = (n + 511) / 512;

    countA_kernel    <<<B1, 512, 0, stream>>>(dst, cntmatA, E, P);
    colscanA_kernel  <<<P, 256, 0, stream>>>(cntmatA, colTotal, B1, P);
    totalscanA_kernel<<<1, 256, 0, stream>>>(colTotal, colStart, P, E);
    scatterA_kernel  <<<B1, 512, 0, stream>>>(src, dst, cntmatA, colStart, packed, E, P);
    localC_kernel    <<<P * BC, 512, 0, stream>>>(packed, colStart, runStart, srcsorted);
    dinvg_kernel     <<<gN, 512, 0, stream>>>(runStart, x, dinv, g, n);
    agg1_kernel      <<<gN, 512, 0, stream>>>(runStart, srcsorted, g, dinv, W1, b1, W2, hs2, n);
    agg2_kernel      <<<gN, 512, 0, stream>>>(runStart, srcsorted, hs2, dinv, b2, out, n);
}